// Round 1
// baseline (562.472 us; speedup 1.0000x reference)
//
#include <hip/hip_runtime.h>
#include <stdint.h>

// AttractorDynamics: sigma = iterate(tanh(drive + (sigma @ J^T)/tau), 10)
// B=16384, M=1024, A=512, tau=0.1, sigma0=0.
// Strategy: bf16 MFMA with hi/lo split operands for fp32-grade accuracy.
//   drive = x_h@W_h^T + x_h@W_l^T + x_l@W_h^T + b   (3-term split, err ~2^-18)
//   step:  rec = sigma_bf16 @ (Js_h + Js_l)^T        (J split, Js = J/tau)
// ws layout (70.3 MB): drive f32 | sigA bf16 | sigB bf16 | Whi Wlo | Jhi Jlo

#define B_DIM 16384
#define M_DIM 1024
#define A_DIM 512

typedef short bf16x8 __attribute__((ext_vector_type(8)));
typedef float f32x4 __attribute__((ext_vector_type(4)));

__device__ __forceinline__ unsigned short f2bf(float f) {
  unsigned int u = __float_as_uint(f);
  unsigned int r = (u + 0x7FFFu + ((u >> 16) & 1u)) >> 16;  // RNE
  return (unsigned short)r;
}
__device__ __forceinline__ float bf2f(unsigned short s) {
  return __uint_as_float(((unsigned int)s) << 16);
}
__device__ __forceinline__ float fast_tanh(float x) {
  // tanh(x) = 1 - 2/(e^{2x}+1); stable at +/-inf of the exp.
  float t = __expf(2.0f * x);
  return fmaf(-2.0f, __builtin_amdgcn_rcpf(t + 1.0f), 1.0f);
}

// ---- prep: split fp32 -> bf16 hi + bf16 lo (optionally pre-scaled) ----
__global__ void split_kernel(const float* __restrict__ src,
                             unsigned short* __restrict__ hi,
                             unsigned short* __restrict__ lo,
                             int n, float scale) {
  int i = blockIdx.x * 256 + threadIdx.x;
  if (i < n) {
    float v = src[i] * scale;
    unsigned short h = f2bf(v);
    hi[i] = h;
    lo[i] = f2bf(v - bf2f(h));
  }
}

// ---- drive GEMM: drive[b][n] = sum_k x[b][k]*W[n][k] + bias[n];
//      sig = bf16(tanh(drive)).  128x128 tile, BK=32, split-A on the fly. ----
__global__ __launch_bounds__(256) void drive_kernel(
    const float* __restrict__ x, const unsigned short* __restrict__ Whi,
    const unsigned short* __restrict__ Wlo, const float* __restrict__ bias,
    float* __restrict__ drive, unsigned short* __restrict__ sig) {
  __shared__ __align__(16) unsigned short Ah[128][40];  // +8 pad: 2-way banks
  __shared__ __align__(16) unsigned short Al[128][40];
  __shared__ __align__(16) unsigned short Bh[128][40];
  __shared__ __align__(16) unsigned short Bl[128][40];

  const int t = threadIdx.x;
  const int bm = blockIdx.y, bn = blockIdx.x;
  const int row = t >> 1, half = t & 1;
  const int lane = t & 63, wave = t >> 6;
  const int wm = wave >> 1, wn = wave & 1;
  const int quad = lane >> 4, l16 = lane & 15;

  f32x4 acc[4][4] = {};

  const float* xp = x + (size_t)(bm * 128 + row) * M_DIM + half * 16;
  const unsigned short* wh = Whi + (size_t)(bn * 128 + row) * M_DIM + half * 16;
  const unsigned short* wl = Wlo + (size_t)(bn * 128 + row) * M_DIM + half * 16;

  for (int k0 = 0; k0 < M_DIM; k0 += 32) {
    // stage A (fp32 -> hi/lo bf16): 16 floats per thread
    float4 v[4];
#pragma unroll
    for (int q = 0; q < 4; ++q) v[q] = *(const float4*)(xp + k0 + 4 * q);
    unsigned short hiv[16], lov[16];
#pragma unroll
    for (int q = 0; q < 4; ++q) {
      float fv[4] = {v[q].x, v[q].y, v[q].z, v[q].w};
#pragma unroll
      for (int e = 0; e < 4; ++e) {
        unsigned short h = f2bf(fv[e]);
        hiv[4 * q + e] = h;
        lov[4 * q + e] = f2bf(fv[e] - bf2f(h));
      }
    }
    *(uint4*)&Ah[row][half * 16]     = *(uint4*)&hiv[0];
    *(uint4*)&Ah[row][half * 16 + 8] = *(uint4*)&hiv[8];
    *(uint4*)&Al[row][half * 16]     = *(uint4*)&lov[0];
    *(uint4*)&Al[row][half * 16 + 8] = *(uint4*)&lov[8];
    // stage B (pre-split W rows, [n][k] layout = W row-major)
    *(uint4*)&Bh[row][half * 16]     = *(const uint4*)(wh + k0);
    *(uint4*)&Bh[row][half * 16 + 8] = *(const uint4*)(wh + k0 + 8);
    *(uint4*)&Bl[row][half * 16]     = *(const uint4*)(wl + k0);
    *(uint4*)&Bl[row][half * 16 + 8] = *(const uint4*)(wl + k0 + 8);
    __syncthreads();

    bf16x8 ah[4], al[4], bh[4], bl[4];
#pragma unroll
    for (int i = 0; i < 4; ++i) {
      ah[i] = *(const bf16x8*)&Ah[wm * 64 + i * 16 + l16][quad * 8];
      al[i] = *(const bf16x8*)&Al[wm * 64 + i * 16 + l16][quad * 8];
    }
#pragma unroll
    for (int j = 0; j < 4; ++j) {
      bh[j] = *(const bf16x8*)&Bh[wn * 64 + j * 16 + l16][quad * 8];
      bl[j] = *(const bf16x8*)&Bl[wn * 64 + j * 16 + l16][quad * 8];
    }
#pragma unroll
    for (int i = 0; i < 4; ++i)
#pragma unroll
      for (int j = 0; j < 4; ++j) {
        acc[i][j] = __builtin_amdgcn_mfma_f32_16x16x32_bf16(ah[i], bh[j], acc[i][j], 0, 0, 0);
        acc[i][j] = __builtin_amdgcn_mfma_f32_16x16x32_bf16(ah[i], bl[j], acc[i][j], 0, 0, 0);
        acc[i][j] = __builtin_amdgcn_mfma_f32_16x16x32_bf16(al[i], bh[j], acc[i][j], 0, 0, 0);
      }
    __syncthreads();
  }

  // epilogue: drive (f32) + sigma1 = tanh(drive) (bf16)
#pragma unroll
  for (int i = 0; i < 4; ++i)
#pragma unroll
    for (int j = 0; j < 4; ++j) {
      int gcol = bn * 128 + wn * 64 + j * 16 + l16;
      float bv = bias[gcol];
#pragma unroll
      for (int r = 0; r < 4; ++r) {
        int grow = bm * 128 + wm * 64 + i * 16 + quad * 4 + r;
        float dv = acc[i][j][r] + bv;
        size_t idx = (size_t)grow * A_DIM + gcol;
        drive[idx] = dv;
        sig[idx] = f2bf(fast_tanh(dv));
      }
    }
}

// ---- step GEMM: v = drive + sigma @ (Jh+Jl)^T; out = tanh(v) ----
__global__ __launch_bounds__(256) void step_kernel(
    const unsigned short* __restrict__ sin_, const unsigned short* __restrict__ Jhi,
    const unsigned short* __restrict__ Jlo, const float* __restrict__ drive,
    unsigned short* __restrict__ sout, float* __restrict__ outf, int last) {
  __shared__ __align__(16) unsigned short As[128][40];
  __shared__ __align__(16) unsigned short Bh[128][40];
  __shared__ __align__(16) unsigned short Bl[128][40];

  const int t = threadIdx.x;
  const int bm = blockIdx.y, bn = blockIdx.x;
  const int row = t >> 1, half = t & 1;
  const int lane = t & 63, wave = t >> 6;
  const int wm = wave >> 1, wn = wave & 1;
  const int quad = lane >> 4, l16 = lane & 15;

  f32x4 acc[4][4] = {};

  const unsigned short* ap = sin_ + (size_t)(bm * 128 + row) * A_DIM + half * 16;
  const unsigned short* jh = Jhi + (size_t)(bn * 128 + row) * A_DIM + half * 16;
  const unsigned short* jl = Jlo + (size_t)(bn * 128 + row) * A_DIM + half * 16;

  for (int k0 = 0; k0 < A_DIM; k0 += 32) {
    *(uint4*)&As[row][half * 16]     = *(const uint4*)(ap + k0);
    *(uint4*)&As[row][half * 16 + 8] = *(const uint4*)(ap + k0 + 8);
    *(uint4*)&Bh[row][half * 16]     = *(const uint4*)(jh + k0);
    *(uint4*)&Bh[row][half * 16 + 8] = *(const uint4*)(jh + k0 + 8);
    *(uint4*)&Bl[row][half * 16]     = *(const uint4*)(jl + k0);
    *(uint4*)&Bl[row][half * 16 + 8] = *(const uint4*)(jl + k0 + 8);
    __syncthreads();

    bf16x8 av[4], bh[4], bl[4];
#pragma unroll
    for (int i = 0; i < 4; ++i)
      av[i] = *(const bf16x8*)&As[wm * 64 + i * 16 + l16][quad * 8];
#pragma unroll
    for (int j = 0; j < 4; ++j) {
      bh[j] = *(const bf16x8*)&Bh[wn * 64 + j * 16 + l16][quad * 8];
      bl[j] = *(const bf16x8*)&Bl[wn * 64 + j * 16 + l16][quad * 8];
    }
#pragma unroll
    for (int i = 0; i < 4; ++i)
#pragma unroll
      for (int j = 0; j < 4; ++j) {
        acc[i][j] = __builtin_amdgcn_mfma_f32_16x16x32_bf16(av[i], bh[j], acc[i][j], 0, 0, 0);
        acc[i][j] = __builtin_amdgcn_mfma_f32_16x16x32_bf16(av[i], bl[j], acc[i][j], 0, 0, 0);
      }
    __syncthreads();
  }

#pragma unroll
  for (int i = 0; i < 4; ++i)
#pragma unroll
    for (int j = 0; j < 4; ++j) {
      int gcol = bn * 128 + wn * 64 + j * 16 + l16;
#pragma unroll
      for (int r = 0; r < 4; ++r) {
        int grow = bm * 128 + wm * 64 + i * 16 + quad * 4 + r;
        size_t idx = (size_t)grow * A_DIM + gcol;
        float v = fast_tanh(drive[idx] + acc[i][j][r]);
        if (last) outf[idx] = v;
        else sout[idx] = f2bf(v);
      }
    }
}

extern "C" void kernel_launch(void* const* d_in, const int* in_sizes, int n_in,
                              void* d_out, int out_size, void* d_ws, size_t ws_size,
                              hipStream_t stream) {
  const float* x = (const float*)d_in[0];
  const float* W = (const float*)d_in[1];
  const float* b = (const float*)d_in[2];
  const float* J = (const float*)d_in[3];
  float* out = (float*)d_out;

  char* ws = (char*)d_ws;
  float* drive         = (float*)(ws);                       // 33,554,432 B
  unsigned short* sigA = (unsigned short*)(ws + 33554432);   // 16,777,216 B
  unsigned short* sigB = (unsigned short*)(ws + 50331648);   // 16,777,216 B
  unsigned short* Whi  = (unsigned short*)(ws + 67108864);   //  1,048,576 B
  unsigned short* Wlo  = (unsigned short*)(ws + 68157440);
  unsigned short* Jhi  = (unsigned short*)(ws + 69206016);   //    524,288 B
  unsigned short* Jlo  = (unsigned short*)(ws + 69730304);   // end: 70,254,592

  const int nW = A_DIM * M_DIM;  // 524288
  const int nJ = A_DIM * A_DIM;  // 262144
  split_kernel<<<(nW + 255) / 256, 256, 0, stream>>>(W, Whi, Wlo, nW, 1.0f);
  split_kernel<<<(nJ + 255) / 256, 256, 0, stream>>>(J, Jhi, Jlo, nJ, 10.0f);  // Js = J/tau

  dim3 grid(A_DIM / 128, B_DIM / 128);  // (4, 128)
  drive_kernel<<<grid, 256, 0, stream>>>(x, Whi, Wlo, b, drive, sigA);

  unsigned short* cur = sigA;
  unsigned short* nxt = sigB;
  for (int s = 0; s < 9; ++s) {  // sigma1 done in drive epilogue; 9 recurrent steps
    step_kernel<<<grid, 256, 0, stream>>>(cur, Jhi, Jlo, drive, nxt, out, s == 8);
    unsigned short* tmp = cur; cur = nxt; nxt = tmp;
  }
}

// Round 2
// 520.054 us; speedup vs baseline: 1.0816x; 1.0816x over previous
//
#include <hip/hip_runtime.h>
#include <stdint.h>

// AttractorDynamics: sigma = iterate(tanh(drive + (sigma @ J^T)/tau), 10)
// B=16384, M=1024, A=512, tau=0.1, sigma0=0.
// R2: step_kernel rewritten to m97-class structure: global_load_lds width=16
// async staging, BK=64, XOR-swizzled granules (2-way LDS banks = free).
// drive_kernel unchanged from R1 (next round's target).

#define B_DIM 16384
#define M_DIM 1024
#define A_DIM 512

typedef short bf16x8 __attribute__((ext_vector_type(8)));
typedef float f32x4 __attribute__((ext_vector_type(4)));

#define GLDS16(g, l)                                                        \
  __builtin_amdgcn_global_load_lds(                                         \
      (const __attribute__((address_space(1))) unsigned int*)(g),           \
      (__attribute__((address_space(3))) unsigned int*)(l), 16, 0, 0)

__device__ __forceinline__ unsigned short f2bf(float f) {
  unsigned int u = __float_as_uint(f);
  unsigned int r = (u + 0x7FFFu + ((u >> 16) & 1u)) >> 16;  // RNE
  return (unsigned short)r;
}
__device__ __forceinline__ float bf2f(unsigned short s) {
  return __uint_as_float(((unsigned int)s) << 16);
}
__device__ __forceinline__ float fast_tanh(float x) {
  float t = __expf(2.0f * x);
  return fmaf(-2.0f, __builtin_amdgcn_rcpf(t + 1.0f), 1.0f);
}

// ---- prep: split fp32 -> bf16 hi + bf16 lo (optionally pre-scaled) ----
__global__ void split_kernel(const float* __restrict__ src,
                             unsigned short* __restrict__ hi,
                             unsigned short* __restrict__ lo,
                             int n, float scale) {
  int i = blockIdx.x * 256 + threadIdx.x;
  if (i < n) {
    float v = src[i] * scale;
    unsigned short h = f2bf(v);
    hi[i] = h;
    lo[i] = f2bf(v - bf2f(h));
  }
}

// ---- drive GEMM (unchanged from R1): drive = x@W^T + b; sig1 = tanh ----
__global__ __launch_bounds__(256) void drive_kernel(
    const float* __restrict__ x, const unsigned short* __restrict__ Whi,
    const unsigned short* __restrict__ Wlo, const float* __restrict__ bias,
    float* __restrict__ drive, unsigned short* __restrict__ sig) {
  __shared__ __align__(16) unsigned short Ah[128][40];
  __shared__ __align__(16) unsigned short Al[128][40];
  __shared__ __align__(16) unsigned short Bh[128][40];
  __shared__ __align__(16) unsigned short Bl[128][40];

  const int t = threadIdx.x;
  const int bm = blockIdx.y, bn = blockIdx.x;
  const int row = t >> 1, half = t & 1;
  const int lane = t & 63, wave = t >> 6;
  const int wm = wave >> 1, wn = wave & 1;
  const int quad = lane >> 4, l16 = lane & 15;

  f32x4 acc[4][4] = {};

  const float* xp = x + (size_t)(bm * 128 + row) * M_DIM + half * 16;
  const unsigned short* wh = Whi + (size_t)(bn * 128 + row) * M_DIM + half * 16;
  const unsigned short* wl = Wlo + (size_t)(bn * 128 + row) * M_DIM + half * 16;

  for (int k0 = 0; k0 < M_DIM; k0 += 32) {
    float4 v[4];
#pragma unroll
    for (int q = 0; q < 4; ++q) v[q] = *(const float4*)(xp + k0 + 4 * q);
    unsigned short hiv[16], lov[16];
#pragma unroll
    for (int q = 0; q < 4; ++q) {
      float fv[4] = {v[q].x, v[q].y, v[q].z, v[q].w};
#pragma unroll
      for (int e = 0; e < 4; ++e) {
        unsigned short h = f2bf(fv[e]);
        hiv[4 * q + e] = h;
        lov[4 * q + e] = f2bf(fv[e] - bf2f(h));
      }
    }
    *(uint4*)&Ah[row][half * 16]     = *(uint4*)&hiv[0];
    *(uint4*)&Ah[row][half * 16 + 8] = *(uint4*)&hiv[8];
    *(uint4*)&Al[row][half * 16]     = *(uint4*)&lov[0];
    *(uint4*)&Al[row][half * 16 + 8] = *(uint4*)&lov[8];
    *(uint4*)&Bh[row][half * 16]     = *(const uint4*)(wh + k0);
    *(uint4*)&Bh[row][half * 16 + 8] = *(const uint4*)(wh + k0 + 8);
    *(uint4*)&Bl[row][half * 16]     = *(const uint4*)(wl + k0);
    *(uint4*)&Bl[row][half * 16 + 8] = *(const uint4*)(wl + k0 + 8);
    __syncthreads();

    bf16x8 ah[4], al[4], bh[4], bl[4];
#pragma unroll
    for (int i = 0; i < 4; ++i) {
      ah[i] = *(const bf16x8*)&Ah[wm * 64 + i * 16 + l16][quad * 8];
      al[i] = *(const bf16x8*)&Al[wm * 64 + i * 16 + l16][quad * 8];
    }
#pragma unroll
    for (int j = 0; j < 4; ++j) {
      bh[j] = *(const bf16x8*)&Bh[wn * 64 + j * 16 + l16][quad * 8];
      bl[j] = *(const bf16x8*)&Bl[wn * 64 + j * 16 + l16][quad * 8];
    }
#pragma unroll
    for (int i = 0; i < 4; ++i)
#pragma unroll
      for (int j = 0; j < 4; ++j) {
        acc[i][j] = __builtin_amdgcn_mfma_f32_16x16x32_bf16(ah[i], bh[j], acc[i][j], 0, 0, 0);
        acc[i][j] = __builtin_amdgcn_mfma_f32_16x16x32_bf16(ah[i], bl[j], acc[i][j], 0, 0, 0);
        acc[i][j] = __builtin_amdgcn_mfma_f32_16x16x32_bf16(al[i], bh[j], acc[i][j], 0, 0, 0);
      }
    __syncthreads();
  }

#pragma unroll
  for (int i = 0; i < 4; ++i)
#pragma unroll
    for (int j = 0; j < 4; ++j) {
      int gcol = bn * 128 + wn * 64 + j * 16 + l16;
      float bv = bias[gcol];
#pragma unroll
      for (int r = 0; r < 4; ++r) {
        int grow = bm * 128 + wm * 64 + i * 16 + quad * 4 + r;
        float dv = acc[i][j][r] + bv;
        size_t idx = (size_t)grow * A_DIM + gcol;
        drive[idx] = dv;
        sig[idx] = f2bf(fast_tanh(dv));
      }
    }
}

// ---- step GEMM (m97-style): v = drive + sigma @ (Jh+Jl)^T; out = tanh(v)
// 128x128 tile, BK=64, global_load_lds(16B) staging, XOR granule swizzle.
// LDS layout: tile[row][granule g] holds Global[row][g ^ (row&7)], granule =
// 8 bf16 = 16 B. Reader XORs back; ds_read_b128 lands 2-way on banks (free).
__global__ __launch_bounds__(256) void step_kernel(
    const unsigned short* __restrict__ sin_, const unsigned short* __restrict__ Jhi,
    const unsigned short* __restrict__ Jlo, const float* __restrict__ drive,
    unsigned short* __restrict__ sout, float* __restrict__ outf, int last) {
  __shared__ __align__(16) unsigned short As[128 * 64];
  __shared__ __align__(16) unsigned short Bhs[128 * 64];
  __shared__ __align__(16) unsigned short Bls[128 * 64];

  const int t = threadIdx.x;
  const int bm = blockIdx.y, bn = blockIdx.x;
  const int lane = t & 63, wave = t >> 6;
  const int wm = wave >> 1, wn = wave & 1;
  const int quad = lane >> 4, l16 = lane & 15;
  const int rl = lane >> 3;              // row-within-chunk 0..7
  const int gsrc = (lane & 7) ^ rl;      // swizzled source granule

  f32x4 acc[4][4] = {};

  const unsigned short* aT = sin_ + (size_t)(bm * 128) * A_DIM;
  const unsigned short* bhT = Jhi + (size_t)(bn * 128) * A_DIM;
  const unsigned short* blT = Jlo + (size_t)(bn * 128) * A_DIM;

  for (int k0 = 0; k0 < A_DIM; k0 += 64) {
#pragma unroll
    for (int q = 0; q < 4; ++q) {
      const int c = wave * 4 + q;                 // 1KB chunk id, 0..15
      const size_t goff = (size_t)(c * 8 + rl) * A_DIM + k0 + gsrc * 8;
      GLDS16(aT + goff, &As[c * 512]);
      GLDS16(bhT + goff, &Bhs[c * 512]);
      GLDS16(blT + goff, &Bls[c * 512]);
    }
    __syncthreads();

#pragma unroll
    for (int h = 0; h < 2; ++h) {
      bf16x8 af[4], bhf[4], blf[4];
#pragma unroll
      for (int i = 0; i < 4; ++i) {
        const int r = wm * 64 + i * 16 + l16;
        af[i] = *(const bf16x8*)&As[r * 64 + 8 * ((4 * h + quad) ^ (r & 7))];
      }
#pragma unroll
      for (int j = 0; j < 4; ++j) {
        const int r = wn * 64 + j * 16 + l16;
        const int off = r * 64 + 8 * ((4 * h + quad) ^ (r & 7));
        bhf[j] = *(const bf16x8*)&Bhs[off];
        blf[j] = *(const bf16x8*)&Bls[off];
      }
#pragma unroll
      for (int i = 0; i < 4; ++i)
#pragma unroll
        for (int j = 0; j < 4; ++j) {
          acc[i][j] = __builtin_amdgcn_mfma_f32_16x16x32_bf16(af[i], bhf[j], acc[i][j], 0, 0, 0);
          acc[i][j] = __builtin_amdgcn_mfma_f32_16x16x32_bf16(af[i], blf[j], acc[i][j], 0, 0, 0);
        }
    }
    __syncthreads();
  }

#pragma unroll
  for (int i = 0; i < 4; ++i)
#pragma unroll
    for (int j = 0; j < 4; ++j) {
      int gcol = bn * 128 + wn * 64 + j * 16 + l16;
#pragma unroll
      for (int r = 0; r < 4; ++r) {
        int grow = bm * 128 + wm * 64 + i * 16 + quad * 4 + r;
        size_t idx = (size_t)grow * A_DIM + gcol;
        float v = fast_tanh(drive[idx] + acc[i][j][r]);
        if (last) outf[idx] = v;
        else sout[idx] = f2bf(v);
      }
    }
}

extern "C" void kernel_launch(void* const* d_in, const int* in_sizes, int n_in,
                              void* d_out, int out_size, void* d_ws, size_t ws_size,
                              hipStream_t stream) {
  const float* x = (const float*)d_in[0];
  const float* W = (const float*)d_in[1];
  const float* b = (const float*)d_in[2];
  const float* J = (const float*)d_in[3];
  float* out = (float*)d_out;

  char* ws = (char*)d_ws;
  float* drive         = (float*)(ws);                       // 33,554,432 B
  unsigned short* sigA = (unsigned short*)(ws + 33554432);   // 16,777,216 B
  unsigned short* sigB = (unsigned short*)(ws + 50331648);   // 16,777,216 B
  unsigned short* Whi  = (unsigned short*)(ws + 67108864);   //  1,048,576 B
  unsigned short* Wlo  = (unsigned short*)(ws + 68157440);
  unsigned short* Jhi  = (unsigned short*)(ws + 69206016);   //    524,288 B
  unsigned short* Jlo  = (unsigned short*)(ws + 69730304);   // end: 70,254,592

  const int nW = A_DIM * M_DIM;
  const int nJ = A_DIM * A_DIM;
  split_kernel<<<(nW + 255) / 256, 256, 0, stream>>>(W, Whi, Wlo, nW, 1.0f);
  split_kernel<<<(nJ + 255) / 256, 256, 0, stream>>>(J, Jhi, Jlo, nJ, 10.0f);

  dim3 grid(A_DIM / 128, B_DIM / 128);  // (4, 128)
  drive_kernel<<<grid, 256, 0, stream>>>(x, Whi, Wlo, b, drive, sigA);

  unsigned short* cur = sigA;
  unsigned short* nxt = sigB;
  for (int s = 0; s < 9; ++s) {
    step_kernel<<<grid, 256, 0, stream>>>(cur, Jhi, Jlo, drive, nxt, out, s == 8);
    unsigned short* tmp = cur; cur = nxt; nxt = tmp;
  }
}